// Round 8
// baseline (1397.981 us; speedup 1.0000x reference)
//
#include <hip/hip_runtime.h>
#include <hip/hip_bf16.h>

#define N_NODESC 100000
#define N_EDGESC 200000
#define BG 2048
#define NDIM 64
#define EDIM 16

typedef __bf16 bf16x8 __attribute__((ext_vector_type(8)));
typedef float f32x4 __attribute__((ext_vector_type(4)));

static __device__ __forceinline__ float bn_inv() { return 0.9999950000374997f; }

// ---------------- zero fills --------------------------------------------------
__global__ void zero_f4(float4* __restrict__ p, int n4) {
    int i = blockIdx.x * 256 + threadIdx.x;
    if (i < n4) p[i] = make_float4(0.f, 0.f, 0.f, 0.f);
}
__global__ void zero_int(int* __restrict__ p, int n) {
    int i = blockIdx.x * 256 + threadIdx.x;
    if (i < n) p[i] = 0;
}
__global__ void zero_out(float* __restrict__ p, int n) {
    int i = blockIdx.x * 256 + threadIdx.x;
    if (i < n) p[i] = 0.f;
}

// ---------------- CSR build: histogram -> scan -> scatter --------------------
__global__ void hist_dst(const int* __restrict__ dst, int* __restrict__ deg) {
    int i = blockIdx.x * 256 + threadIdx.x;
    if (i < N_EDGESC) atomicAdd(&deg[dst[i]], 1);
}
__global__ void scan_bsums(const int* __restrict__ deg, int* __restrict__ bsum, int n) {
    __shared__ int ls[256];
    int b = blockIdx.x, t = threadIdx.x;
    int s = 0;
#pragma unroll
    for (int j = 0; j < 4; j++) {
        int i = b * 1024 + t * 4 + j;
        if (i < n) s += deg[i];
    }
    ls[t] = s;
    __syncthreads();
    for (int off = 128; off; off >>= 1) {
        if (t < off) ls[t] += ls[t + off];
        __syncthreads();
    }
    if (t == 0) bsum[b] = ls[0];
}
__global__ void scan_top(int* __restrict__ bsum, int nb, int* __restrict__ total) {
    if (threadIdx.x == 0) {
        int acc = 0;
        for (int i = 0; i < nb; i++) { int v = bsum[i]; bsum[i] = acc; acc += v; }
        *total = acc;
    }
}
__global__ void scan_final(const int* __restrict__ deg, const int* __restrict__ bsum,
                           int* __restrict__ rowptr, int* __restrict__ cursor, int n) {
    __shared__ int ls[256];
    int b = blockIdx.x, t = threadIdx.x;
    int v[4], s = 0;
#pragma unroll
    for (int j = 0; j < 4; j++) {
        int i = b * 1024 + t * 4 + j;
        v[j] = (i < n) ? deg[i] : 0;
        s += v[j];
    }
    ls[t] = s;
    __syncthreads();
    int run = s;
    for (int off = 1; off < 256; off <<= 1) {
        int add = (t >= off) ? ls[t - off] : 0;
        __syncthreads();
        ls[t] += add;
        __syncthreads();
    }
    int excl = ls[t] - run + bsum[b];
#pragma unroll
    for (int j = 0; j < 4; j++) {
        int i = b * 1024 + t * 4 + j;
        if (i < n) { rowptr[i] = excl; cursor[i] = excl; excl += v[j]; }
    }
}
__global__ void scatter_eid(const int* __restrict__ dst, int* __restrict__ cursor,
                            int* __restrict__ eid) {
    int e = blockIdx.x * 256 + threadIdx.x;
    if (e < N_EDGESC) {
        int p = atomicAdd(&cursor[dst[e]], 1);
        eid[p] = e;
    }
}

// ---------------- W [K][N] f32 -> bf16 [N][K] --------------------------------
__global__ void transpose_w(const float* __restrict__ W, __hip_bfloat16* __restrict__ hi,
                            int K, int N) {
    __shared__ float t[64][65];
    int k0 = blockIdx.x * 64, n0 = blockIdx.y * 64;
    int tid = threadIdx.x, tx = tid & 63, ty = tid >> 6;
    for (int r = ty; r < 64; r += 4) t[r][tx] = W[(size_t)(k0 + r) * N + n0 + tx];
    __syncthreads();
    for (int r = ty; r < 64; r += 4)
        hi[(size_t)(n0 + r) * K + k0 + tx] = __float2bfloat16(t[tx][r]);
}

__global__ void concat_bias(const float* __restrict__ a, const float* __restrict__ b,
                            float* __restrict__ o) {
    int i = blockIdx.x * 256 + threadIdx.x;
    if (i < 2048) { o[i] = a[i]; o[2048 + i] = b[i]; }
}

// ---------------- GINE1 gather -----------------------------------------------
#define G1_NPW 8
__global__ __launch_bounds__(256, 2) void gine1_gather(
    const float* __restrict__ x, const int* __restrict__ srcv, const float* __restrict__ ea,
    const float* __restrict__ e1W, const float* __restrict__ e1b,
    const int* __restrict__ rowptr, const int* __restrict__ eid,
    __hip_bfloat16* __restrict__ xin) {
    int tid = threadIdx.x;
    int wave = tid >> 6, lane = tid & 63;
    float wreg[16];
#pragma unroll
    for (int k = 0; k < 16; k++) wreg[k] = e1W[k * 64 + lane];
    float bb = e1b[lane];
    int nbase = (blockIdx.x * 4 + wave) * G1_NPW;
#pragma unroll 1
    for (int it = 0; it < G1_NPW; it++) {
        int n = nbase + it;
        if (n >= N_NODESC) return;
        float acc = x[(size_t)n * 64 + lane];
        int beg = rowptr[n], end = rowptr[n + 1];
        for (int idx = beg; idx < end; idx++) {
            int e = eid[idx], s = srcv[e];
            const float4* ef = (const float4*)(ea + (size_t)e * 16);
            float4 e0 = ef[0], e1 = ef[1], e2 = ef[2], e3 = ef[3];
            float p = bb;
            p = fmaf(e0.x, wreg[0], p);  p = fmaf(e0.y, wreg[1], p);
            p = fmaf(e0.z, wreg[2], p);  p = fmaf(e0.w, wreg[3], p);
            p = fmaf(e1.x, wreg[4], p);  p = fmaf(e1.y, wreg[5], p);
            p = fmaf(e1.z, wreg[6], p);  p = fmaf(e1.w, wreg[7], p);
            p = fmaf(e2.x, wreg[8], p);  p = fmaf(e2.y, wreg[9], p);
            p = fmaf(e2.z, wreg[10], p); p = fmaf(e2.w, wreg[11], p);
            p = fmaf(e3.x, wreg[12], p); p = fmaf(e3.y, wreg[13], p);
            p = fmaf(e3.z, wreg[14], p); p = fmaf(e3.w, wreg[15], p);
            acc += fmaxf(x[(size_t)s * 64 + lane] + p, 0.f);
        }
        xin[(size_t)n * 64 + lane] = __float2bfloat16(acc);
    }
}

// ---------------- GINE2 gather -----------------------------------------------
#define G2_NPB 16
__global__ __launch_bounds__(256, 2) void gine2_gather(
    const __hip_bfloat16* __restrict__ h, const int* __restrict__ srcv,
    const float* __restrict__ ea, const float* __restrict__ e2W,
    const float* __restrict__ e2b, const int* __restrict__ rowptr,
    const int* __restrict__ eid, __hip_bfloat16* __restrict__ a2, int n0, int n1) {
    int tid = threadIdx.x;
    int half = tid >> 7, lt = tid & 127;
    float wreg[4][16], breg[4];
#pragma unroll
    for (int j = 0; j < 4; j++) {
        int c = lt * 4 + j;
        breg[j] = e2b[c];
#pragma unroll
        for (int k = 0; k < 16; k++) wreg[j][k] = e2W[k * 512 + c];
    }
    int nbase = n0 + blockIdx.x * G2_NPB + half;
#pragma unroll 1
    for (int it = 0; it < G2_NPB / 2; it++) {
        int n = nbase + it * 2;
        if (n >= n1) return;
        short4 hv = *(const short4*)((const short*)(h + (size_t)n * 512) + lt * 4);
        const __hip_bfloat16* hb = (const __hip_bfloat16*)&hv;
        float acc[4];
#pragma unroll
        for (int j = 0; j < 4; j++) acc[j] = __bfloat162float(hb[j]);
        int beg = rowptr[n], end = rowptr[n + 1];
        for (int idx = beg; idx < end; idx++) {
            int e = eid[idx], s = srcv[e];
            const float4* ef = (const float4*)(ea + (size_t)e * 16);
            float4 e0 = ef[0], e1 = ef[1], e2v = ef[2], e3 = ef[3];
            short4 sv = *(const short4*)((const short*)(h + (size_t)s * 512) + lt * 4);
            const __hip_bfloat16* sb = (const __hip_bfloat16*)&sv;
#pragma unroll
            for (int j = 0; j < 4; j++) {
                float p = breg[j];
                p = fmaf(e0.x, wreg[j][0], p);  p = fmaf(e0.y, wreg[j][1], p);
                p = fmaf(e0.z, wreg[j][2], p);  p = fmaf(e0.w, wreg[j][3], p);
                p = fmaf(e1.x, wreg[j][4], p);  p = fmaf(e1.y, wreg[j][5], p);
                p = fmaf(e1.z, wreg[j][6], p);  p = fmaf(e1.w, wreg[j][7], p);
                p = fmaf(e2v.x, wreg[j][8], p); p = fmaf(e2v.y, wreg[j][9], p);
                p = fmaf(e2v.z, wreg[j][10], p);p = fmaf(e2v.w, wreg[j][11], p);
                p = fmaf(e3.x, wreg[j][12], p); p = fmaf(e3.y, wreg[j][13], p);
                p = fmaf(e3.z, wreg[j][14], p); p = fmaf(e3.w, wreg[j][15], p);
                acc[j] += fmaxf(__bfloat162float(sb[j]) + p, 0.f);
            }
        }
        __hip_bfloat16 o[4];
#pragma unroll
        for (int j = 0; j < 4; j++) o[j] = __float2bfloat16(acc[j]);
        *(short4*)((short*)(a2 + (size_t)(n - n0) * 512) + lt * 4) = *(const short4*)o;
    }
}

// ---------------- MFMA GEMM: C[M,N] = A[M,K](bf16) @ B^T[N,K](bf16) ----------
// NO LDS, NO BARRIERS: each wave loads its own A/B fragments straight from
// global into registers (L2-hot for B, streaming for A), software-prefetched
// one k-step ahead. Waves slip independently -> compiler emits fine vmcnt(N).
// Fragment load pattern: 16 lanes (fi) x 4 kb-quads cover one full 64B line
// per row -> fully utilized cache lines. GRID: x = col-tile, y = row-tile.
template <int MODE>
__global__ __launch_bounds__(256, 2) void mfma_gemm(
    const __hip_bfloat16* __restrict__ A, const __hip_bfloat16* __restrict__ Bhi,
    int M, int K, int N, const float* __restrict__ bias, const float* __restrict__ bng,
    const float* __restrict__ bnb, const int* __restrict__ batch,
    float* __restrict__ psum, __hip_bfloat16* __restrict__ Cout) {
    int r0 = blockIdx.y * 128;
    int n0 = blockIdx.x * 128;
    int tid = threadIdx.x;
    int lane = tid & 63;
    int wv = tid >> 6;
    int wm = (wv >> 1) * 64, wn = (wv & 1) * 64;
    int fi = lane & 15, kb = (lane >> 4) * 8;

    f32x4 acc[4][4];
#pragma unroll
    for (int i = 0; i < 4; i++)
#pragma unroll
        for (int j = 0; j < 4; j++) acc[i][j] = (f32x4){0.f, 0.f, 0.f, 0.f};

    const __hip_bfloat16* aptr[4];
    const __hip_bfloat16* bptr[4];
#pragma unroll
    for (int mi = 0; mi < 4; mi++) {
        int grow = r0 + wm + mi * 16 + fi;
        if (grow >= M) grow = M - 1;
        aptr[mi] = A + (size_t)grow * K + kb;
    }
#pragma unroll
    for (int ni = 0; ni < 4; ni++)
        bptr[ni] = Bhi + (size_t)(n0 + wn + ni * 16 + fi) * K + kb;

    bf16x8 ac[4], bc[4], an[4], bn2[4];
#pragma unroll
    for (int mi = 0; mi < 4; mi++) ac[mi] = *(const bf16x8*)(aptr[mi]);
#pragma unroll
    for (int ni = 0; ni < 4; ni++) bc[ni] = *(const bf16x8*)(bptr[ni]);

    // K is a multiple of 64; two pipelined phases per iteration.
#pragma unroll 1
    for (int k0 = 0; k0 < K; k0 += 64) {
        // phase 1: prefetch k0+32, compute on k0
#pragma unroll
        for (int mi = 0; mi < 4; mi++) an[mi] = *(const bf16x8*)(aptr[mi] + k0 + 32);
#pragma unroll
        for (int ni = 0; ni < 4; ni++) bn2[ni] = *(const bf16x8*)(bptr[ni] + k0 + 32);
#pragma unroll
        for (int mi = 0; mi < 4; mi++)
#pragma unroll
            for (int ni = 0; ni < 4; ni++)
                acc[mi][ni] = __builtin_amdgcn_mfma_f32_16x16x32_bf16(ac[mi], bc[ni],
                                                                     acc[mi][ni], 0, 0, 0);
        // phase 2: prefetch k0+64 (if any), compute on k0+32
        if (k0 + 64 < K) {
#pragma unroll
            for (int mi = 0; mi < 4; mi++) ac[mi] = *(const bf16x8*)(aptr[mi] + k0 + 64);
#pragma unroll
            for (int ni = 0; ni < 4; ni++) bc[ni] = *(const bf16x8*)(bptr[ni] + k0 + 64);
        }
#pragma unroll
        for (int mi = 0; mi < 4; mi++)
#pragma unroll
            for (int ni = 0; ni < 4; ni++)
                acc[mi][ni] = __builtin_amdgcn_mfma_f32_16x16x32_bf16(an[mi], bn2[ni],
                                                                     acc[mi][ni], 0, 0, 0);
    }

    int col_l = lane & 15, quad = lane >> 4;
#pragma unroll
    for (int mi = 0; mi < 4; mi++) {
        int rbase = r0 + wm + mi * 16 + quad * 4;
#pragma unroll
        for (int ni = 0; ni < 4; ni++) {
            int gcol = n0 + wn + ni * 16 + col_l;
            if (MODE == 0) {
                float b0 = bias[gcol];
#pragma unroll
                for (int reg = 0; reg < 4; reg++) {
                    int grow = rbase + reg;
                    if (grow < M)
                        Cout[(size_t)grow * N + gcol] = __float2bfloat16(acc[mi][ni][reg] + b0);
                }
            } else {
                float b0 = bias[gcol], g0 = bng[gcol], bb0 = bnb[gcol];
                float vv[4];
#pragma unroll
                for (int reg = 0; reg < 4; reg++)
                    vv[reg] = fmaxf(fmaf((acc[mi][ni][reg] + b0) * bn_inv(), g0, bb0), 0.f);
                if (MODE == 1) {
#pragma unroll
                    for (int reg = 0; reg < 4; reg++) {
                        int grow = rbase + reg;
                        if (grow < M) Cout[(size_t)grow * 512 + gcol] = __float2bfloat16(vv[reg]);
                    }
                } else {
                    if (rbase + 3 < M && batch[rbase] == batch[rbase + 3]) {
                        atomicAdd(&psum[(size_t)batch[rbase] * 512 + gcol],
                                  (vv[0] + vv[1]) + (vv[2] + vv[3]));
                    } else {
#pragma unroll
                        for (int reg = 0; reg < 4; reg++) {
                            int grow = rbase + reg;
                            if (grow < M)
                                atomicAdd(&psum[(size_t)batch[grow] * 512 + gcol], vv[reg]);
                        }
                    }
                }
            }
        }
    }
}

// ---------------- node counts per graph --------------------------------------
__global__ void count_nodes(const int* __restrict__ batch, float* __restrict__ cnt) {
    int i = blockIdx.x * 256 + threadIdx.x;
    if (i < N_NODESC) atomicAdd(&cnt[batch[i]], 1.0f);
}

// ---------------- finalize pool + assemble xn [B,7,512] bf16 -----------------
__global__ void build_xn(const float* __restrict__ psum, const float* __restrict__ cnt,
                         const float* __restrict__ ecfp, const float* __restrict__ topo,
                         const float* __restrict__ maccs, const float* __restrict__ estate,
                         const float* __restrict__ rdkit2d, const float* __restrict__ phar2d,
                         __hip_bfloat16* __restrict__ xn) {
    int i = blockIdx.x * 256 + threadIdx.x;
    if (i >= BG * 512) return;
    int bidx = i >> 9, c = i & 511;
    float cv = fmaxf(cnt[bidx], 1.0f);
    __hip_bfloat16* o = xn + (size_t)bidx * 7 * 512;
    o[c] = __float2bfloat16(psum[i] / cv);
    o[512 + c] = __float2bfloat16(ecfp[i]);
    o[2 * 512 + c] = __float2bfloat16(topo[i]);
    o[3 * 512 + c] = __float2bfloat16(maccs[i]);
    o[4 * 512 + c] = __float2bfloat16(estate[i]);
    o[5 * 512 + c] = __float2bfloat16(rdkit2d[i]);
    o[6 * 512 + c] = __float2bfloat16(phar2d[i]);
}

// ---------------- GAT attention (fused gl|gr layout: C[B*7][4096]) -----------
__global__ void gat_attn(const __hip_bfloat16* __restrict__ cg,
                         const float* __restrict__ att, const float* __restrict__ bias,
                         const float* __restrict__ bng, const float* __restrict__ bnb,
                         __hip_bfloat16* __restrict__ zout) {
    int b = blockIdx.x;
    int tid = threadIdx.x;
    int wave = tid >> 6, lane = tid & 63;
    __shared__ float logits[13][4];
    __shared__ float alpha[13][4];
    const size_t base = (size_t)b * 7 * 4096;
    for (int p = wave; p < 52; p += 4) {
        int e = p >> 2, hh = p & 3;
        int se = (e < 7) ? 0 : (e - 6);
        int de = (e < 6) ? (e + 1) : ((e == 6) ? 0 : (e - 6));
        const __hip_bfloat16* glp = cg + base + (size_t)se * 4096 + hh * 512;
        const __hip_bfloat16* grp = cg + base + (size_t)de * 4096 + 2048 + hh * 512;
        const float* ap = att + hh * 512;
        float s = 0.f;
#pragma unroll
        for (int j = 0; j < 8; j++) {
            int c = lane + j * 64;
            float v = __bfloat162float(glp[c]) + __bfloat162float(grp[c]);
            v = (v >= 0.f) ? v : 0.2f * v;
            s = fmaf(v, ap[c], s);
        }
#pragma unroll
        for (int off = 32; off; off >>= 1) s += __shfl_down(s, off);
        if (lane == 0) logits[e][hh] = s;
    }
    __syncthreads();
    if (tid < 24) {
        int n = 1 + (tid >> 2), hh = tid & 3;
        float la = logits[n - 1][hh], lb = logits[6 + n][hh];
        float m = fmaxf(la, lb);
        float ea = __expf(la - m), eb = __expf(lb - m);
        float inv = 1.f / (ea + eb);
        alpha[n - 1][hh] = ea * inv;
        alpha[6 + n][hh] = eb * inv;
    } else if (tid < 28) {
        alpha[6][tid & 3] = 1.f;
    }
    __syncthreads();
    for (int i = tid; i < 7 * 512; i += 256) {
        int n = i >> 9, c = i & 511;
        float v = 0.f;
        if (n == 0) {
#pragma unroll
            for (int hh = 0; hh < 4; hh++)
                v = fmaf(alpha[6][hh],
                         __bfloat162float(cg[base + (size_t)hh * 512 + c]), v);
        } else {
#pragma unroll
            for (int hh = 0; hh < 4; hh++) {
                v = fmaf(alpha[n - 1][hh],
                         __bfloat162float(cg[base + (size_t)hh * 512 + c]), v);
                v = fmaf(alpha[6 + n][hh],
                         __bfloat162float(cg[base + (size_t)n * 4096 + hh * 512 + c]), v);
            }
        }
        v = fmaf(v, 0.25f, bias[c]);
        v = fmaf(v * bn_inv(), bng[c], bnb[c]);
        zout[(size_t)b * 7 * 512 + i] = __float2bfloat16(fmaxf(v, 0.f));
    }
}

// ---------------- final fc ----------------------------------------------------
__global__ void final_fc(const __hip_bfloat16* __restrict__ z, const float* __restrict__ fcW,
                         const float* __restrict__ fcb, float* __restrict__ out) {
    int b = blockIdx.x * 4 + (threadIdx.x >> 6);
    int lane = threadIdx.x & 63;
    if (b >= BG) return;
    const __hip_bfloat16* row = z + (size_t)b * 7 * 512;
    float s = 0.f;
#pragma unroll
    for (int j = 0; j < 8; j++)
        s = fmaf(__bfloat162float(row[lane + j * 64]), fcW[lane + j * 64], s);
#pragma unroll
    for (int off = 32; off; off >>= 1) s += __shfl_down(s, off);
    if (lane == 0) out[b] = s + fcb[0];
}

extern "C" void kernel_launch(void* const* d_in, const int* in_sizes, int n_in,
                              void* d_out, int out_size, void* d_ws, size_t ws_size,
                              hipStream_t stream) {
    const float* x = (const float*)d_in[0];
    const int* eidx = (const int*)d_in[1];
    const float* eattr = (const float*)d_in[2];
    const int* batch = (const int*)d_in[3];
    const float* ecfp = (const float*)d_in[4];
    const float* topo = (const float*)d_in[5];
    const float* maccs = (const float*)d_in[6];
    const float* estate = (const float*)d_in[7];
    const float* rdkit2d = (const float*)d_in[8];
    const float* phar2d = (const float*)d_in[9];
    const float* g1_W = (const float*)d_in[10];
    const float* g1_b = (const float*)d_in[11];
    const float* e1_W = (const float*)d_in[12];
    const float* e1_b = (const float*)d_in[13];
    const float* bn1_g = (const float*)d_in[14];
    const float* bn1_b = (const float*)d_in[15];
    const float* g2_W = (const float*)d_in[16];
    const float* g2_b = (const float*)d_in[17];
    const float* e2_W = (const float*)d_in[18];
    const float* e2_b = (const float*)d_in[19];
    const float* bn2_g = (const float*)d_in[20];
    const float* bn2_b = (const float*)d_in[21];
    const float* gat1_Wl = (const float*)d_in[22];
    const float* gat1_bl = (const float*)d_in[23];
    const float* gat1_Wr = (const float*)d_in[24];
    const float* gat1_br = (const float*)d_in[25];
    const float* gat1_att = (const float*)d_in[26];
    const float* gat1_bias = (const float*)d_in[27];
    const float* bn3_g = (const float*)d_in[28];
    const float* bn3_b = (const float*)d_in[29];
    const float* gat2_Wl = (const float*)d_in[30];
    const float* gat2_bl = (const float*)d_in[31];
    const float* gat2_Wr = (const float*)d_in[32];
    const float* gat2_br = (const float*)d_in[33];
    const float* gat2_att = (const float*)d_in[34];
    const float* gat2_bias = (const float*)d_in[35];
    const float* bn4_g = (const float*)d_in[36];
    const float* bn4_b = (const float*)d_in[37];
    const float* fc_W = (const float*)d_in[38];
    const float* fc_b = (const float*)d_in[39];
    float* out = (float*)d_out;

    const size_t NEEDED = 194682880ull;
    if (ws_size < NEEDED) {
        zero_out<<<(BG + 255) / 256, 256, 0, stream>>>(out, BG);
        return;
    }
    char* w = (char*)d_ws;
    __hip_bfloat16* H = (__hip_bfloat16*)w;
    __hip_bfloat16* CG = (__hip_bfloat16*)w;
    __hip_bfloat16* A2 = (__hip_bfloat16*)(w + 102400000);
    __hip_bfloat16* GW12 = (__hip_bfloat16*)(w + 117440512);
    __hip_bfloat16* GW34 = (__hip_bfloat16*)(w + 121634816);
    __hip_bfloat16* Z1B = (__hip_bfloat16*)(w + 125829120);
    float* B12 = (float*)(w + 140509184);
    float* B34 = (float*)(w + 140525568);

    char* C = w + 161120256;
    __hip_bfloat16* XIN = (__hip_bfloat16*)C;
    __hip_bfloat16* XNB = (__hip_bfloat16*)C;
    __hip_bfloat16* Z2B = (__hip_bfloat16*)(C + 14680064);
    int* ROWPTR = (int*)(C + 14680064);
    int* CURSOR = (int*)(C + 15080192);
    int* EID = (int*)(C + 15480320);
    int* DEG = (int*)(C + 16280320);
    __hip_bfloat16* G1W = (__hip_bfloat16*)(C + 16680320);
    __hip_bfloat16* G2W = (__hip_bfloat16*)(C + 16745856);
    int* BSUM = (int*)(C + 17270144);

    float* PS = (float*)(w + 190480384);
    float* PC = (float*)(w + 194674688);

    const int* src = eidx;
    const int* dst = eidx + N_EDGESC;

    // ---- CSR build ----
    zero_int<<<(N_NODESC + 255) / 256, 256, 0, stream>>>(DEG, N_NODESC);
    zero_f4<<<(BG * 512 / 4 + 255) / 256, 256, 0, stream>>>((float4*)PS, BG * 512 / 4);
    zero_f4<<<(BG / 4 + 255) / 256, 256, 0, stream>>>((float4*)PC, BG / 4);
    hist_dst<<<(N_EDGESC + 255) / 256, 256, 0, stream>>>(dst, DEG);
    const int NB = (N_NODESC + 1023) / 1024;  // 98
    scan_bsums<<<NB, 256, 0, stream>>>(DEG, BSUM, N_NODESC);
    scan_top<<<1, 64, 0, stream>>>(BSUM, NB, ROWPTR + N_NODESC);
    scan_final<<<NB, 256, 0, stream>>>(DEG, BSUM, ROWPTR, CURSOR, N_NODESC);
    scatter_eid<<<(N_EDGESC + 255) / 256, 256, 0, stream>>>(dst, CURSOR, EID);

    // ---- GINE weight prep ----
    transpose_w<<<dim3(1, 8), 256, 0, stream>>>(g1_W, G1W, 64, 512);
    transpose_w<<<dim3(8, 8), 256, 0, stream>>>(g2_W, G2W, 512, 512);

    // ---- GINE1 ----
    gine1_gather<<<(N_NODESC + 4 * G1_NPW - 1) / (4 * G1_NPW), 256, 0, stream>>>(
        x, src, eattr, e1_W, e1_b, ROWPTR, EID, XIN);
    mfma_gemm<1><<<dim3(4, (N_NODESC + 127) / 128), 256, 0, stream>>>(
        XIN, G1W, N_NODESC, 64, 512, g1_b, bn1_g, bn1_b, nullptr, nullptr, H);
    count_nodes<<<(N_NODESC + 255) / 256, 256, 0, stream>>>(batch, PC);

    // ---- GINE2: 2 chunks of 50k nodes ----
    for (int c0n = 0; c0n < N_NODESC; c0n += 50000) {
        int c1n = c0n + 50000;
        int rows = 50000;
        gine2_gather<<<(rows + G2_NPB - 1) / G2_NPB, 256, 0, stream>>>(
            H, src, eattr, e2_W, e2_b, ROWPTR, EID, A2, c0n, c1n);
        mfma_gemm<2><<<dim3(4, (rows + 127) / 128), 256, 0, stream>>>(
            A2, G2W, rows, 512, 512, g2_b, bn2_g, bn2_b, batch + c0n, PS, nullptr);
    }

    // ---- GAT weight prep (H and A2 dead) ----
    transpose_w<<<dim3(8, 32), 256, 0, stream>>>(gat1_Wl, GW12, 512, 2048);
    transpose_w<<<dim3(8, 32), 256, 0, stream>>>(gat1_Wr, GW12 + (size_t)2048 * 512, 512, 2048);
    transpose_w<<<dim3(8, 32), 256, 0, stream>>>(gat2_Wl, GW34, 512, 2048);
    transpose_w<<<dim3(8, 32), 256, 0, stream>>>(gat2_Wr, GW34 + (size_t)2048 * 512, 512, 2048);
    concat_bias<<<8, 256, 0, stream>>>(gat1_bl, gat1_br, B12);
    concat_bias<<<8, 256, 0, stream>>>(gat2_bl, gat2_br, B34);

    // ---- pool -> xn ----
    build_xn<<<(BG * 512) / 256, 256, 0, stream>>>(PS, PC, ecfp, topo, maccs, estate,
                                                   rdkit2d, phar2d, XNB);
    // ---- GAT layer 1 (fused L|R: N = 4096) ----
    const int MGAT = BG * 7;  // 14336
    dim3 ggrid(4096 / 128, MGAT / 128);
    mfma_gemm<0><<<ggrid, 256, 0, stream>>>(XNB, GW12, MGAT, 512, 4096, B12,
                                            nullptr, nullptr, nullptr, nullptr, CG);
    gat_attn<<<BG, 256, 0, stream>>>(CG, gat1_att, gat1_bias, bn3_g, bn3_b, Z1B);
    // ---- GAT layer 2 ----
    mfma_gemm<0><<<ggrid, 256, 0, stream>>>(Z1B, GW34, MGAT, 512, 4096, B34,
                                            nullptr, nullptr, nullptr, nullptr, CG);
    gat_attn<<<BG, 256, 0, stream>>>(CG, gat2_att, gat2_bias, bn4_g, bn4_b, Z2B);
    // ---- final fc ----
    final_fc<<<BG / 4, 256, 0, stream>>>(Z2B, fc_W, fc_b, out);
}

// Round 9
// 1058.934 us; speedup vs baseline: 1.3202x; 1.3202x over previous
//
#include <hip/hip_runtime.h>
#include <hip/hip_bf16.h>

#define N_NODESC 100000
#define N_EDGESC 200000
#define BG 2048
#define NDIM 64
#define EDIM 16

typedef __bf16 bf16x8 __attribute__((ext_vector_type(8)));
typedef float f32x4 __attribute__((ext_vector_type(4)));

static __device__ __forceinline__ float bn_inv() { return 0.9999950000374997f; }

// async global->LDS 16B per lane; LDS dest = wave-uniform base + lane*16
__device__ __forceinline__ void gl2lds16(const void* g, void* l) {
    __builtin_amdgcn_global_load_lds(
        (const __attribute__((address_space(1))) unsigned int*)g,
        (__attribute__((address_space(3))) unsigned int*)l, 16, 0, 0);
}

// ---------------- zero fills --------------------------------------------------
__global__ void zero_f4(float4* __restrict__ p, int n4) {
    int i = blockIdx.x * 256 + threadIdx.x;
    if (i < n4) p[i] = make_float4(0.f, 0.f, 0.f, 0.f);
}
__global__ void zero_int(int* __restrict__ p, int n) {
    int i = blockIdx.x * 256 + threadIdx.x;
    if (i < n) p[i] = 0;
}
__global__ void zero_out(float* __restrict__ p, int n) {
    int i = blockIdx.x * 256 + threadIdx.x;
    if (i < n) p[i] = 0.f;
}

// ---------------- CSR build: histogram -> scan -> scatter --------------------
__global__ void hist_dst(const int* __restrict__ dst, int* __restrict__ deg) {
    int i = blockIdx.x * 256 + threadIdx.x;
    if (i < N_EDGESC) atomicAdd(&deg[dst[i]], 1);
}
__global__ void scan_bsums(const int* __restrict__ deg, int* __restrict__ bsum, int n) {
    __shared__ int ls[256];
    int b = blockIdx.x, t = threadIdx.x;
    int s = 0;
#pragma unroll
    for (int j = 0; j < 4; j++) {
        int i = b * 1024 + t * 4 + j;
        if (i < n) s += deg[i];
    }
    ls[t] = s;
    __syncthreads();
    for (int off = 128; off; off >>= 1) {
        if (t < off) ls[t] += ls[t + off];
        __syncthreads();
    }
    if (t == 0) bsum[b] = ls[0];
}
__global__ void scan_top(int* __restrict__ bsum, int nb, int* __restrict__ total) {
    if (threadIdx.x == 0) {
        int acc = 0;
        for (int i = 0; i < nb; i++) { int v = bsum[i]; bsum[i] = acc; acc += v; }
        *total = acc;
    }
}
__global__ void scan_final(const int* __restrict__ deg, const int* __restrict__ bsum,
                           int* __restrict__ rowptr, int* __restrict__ cursor, int n) {
    __shared__ int ls[256];
    int b = blockIdx.x, t = threadIdx.x;
    int v[4], s = 0;
#pragma unroll
    for (int j = 0; j < 4; j++) {
        int i = b * 1024 + t * 4 + j;
        v[j] = (i < n) ? deg[i] : 0;
        s += v[j];
    }
    ls[t] = s;
    __syncthreads();
    int run = s;
    for (int off = 1; off < 256; off <<= 1) {
        int add = (t >= off) ? ls[t - off] : 0;
        __syncthreads();
        ls[t] += add;
        __syncthreads();
    }
    int excl = ls[t] - run + bsum[b];
#pragma unroll
    for (int j = 0; j < 4; j++) {
        int i = b * 1024 + t * 4 + j;
        if (i < n) { rowptr[i] = excl; cursor[i] = excl; excl += v[j]; }
    }
}
__global__ void scatter_eid(const int* __restrict__ dst, int* __restrict__ cursor,
                            int* __restrict__ eid) {
    int e = blockIdx.x * 256 + threadIdx.x;
    if (e < N_EDGESC) {
        int p = atomicAdd(&cursor[dst[e]], 1);
        eid[p] = e;
    }
}

// ---------------- W [K][N] f32 -> bf16 [N][K] --------------------------------
__global__ void transpose_w(const float* __restrict__ W, __hip_bfloat16* __restrict__ hi,
                            int K, int N) {
    __shared__ float t[64][65];
    int k0 = blockIdx.x * 64, n0 = blockIdx.y * 64;
    int tid = threadIdx.x, tx = tid & 63, ty = tid >> 6;
    for (int r = ty; r < 64; r += 4) t[r][tx] = W[(size_t)(k0 + r) * N + n0 + tx];
    __syncthreads();
    for (int r = ty; r < 64; r += 4)
        hi[(size_t)(n0 + r) * K + k0 + tx] = __float2bfloat16(t[tx][r]);
}

__global__ void concat_bias(const float* __restrict__ a, const float* __restrict__ b,
                            float* __restrict__ o) {
    int i = blockIdx.x * 256 + threadIdx.x;
    if (i < 2048) { o[i] = a[i]; o[2048 + i] = b[i]; }
}

// ---------------- GINE1 gather -----------------------------------------------
#define G1_NPW 8
__global__ __launch_bounds__(256, 2) void gine1_gather(
    const float* __restrict__ x, const int* __restrict__ srcv, const float* __restrict__ ea,
    const float* __restrict__ e1W, const float* __restrict__ e1b,
    const int* __restrict__ rowptr, const int* __restrict__ eid,
    __hip_bfloat16* __restrict__ xin) {
    int tid = threadIdx.x;
    int wave = tid >> 6, lane = tid & 63;
    float wreg[16];
#pragma unroll
    for (int k = 0; k < 16; k++) wreg[k] = e1W[k * 64 + lane];
    float bb = e1b[lane];
    int nbase = (blockIdx.x * 4 + wave) * G1_NPW;
#pragma unroll 1
    for (int it = 0; it < G1_NPW; it++) {
        int n = nbase + it;
        if (n >= N_NODESC) return;
        float acc = x[(size_t)n * 64 + lane];
        int beg = rowptr[n], end = rowptr[n + 1];
        for (int idx = beg; idx < end; idx++) {
            int e = eid[idx], s = srcv[e];
            const float4* ef = (const float4*)(ea + (size_t)e * 16);
            float4 e0 = ef[0], e1 = ef[1], e2 = ef[2], e3 = ef[3];
            float p = bb;
            p = fmaf(e0.x, wreg[0], p);  p = fmaf(e0.y, wreg[1], p);
            p = fmaf(e0.z, wreg[2], p);  p = fmaf(e0.w, wreg[3], p);
            p = fmaf(e1.x, wreg[4], p);  p = fmaf(e1.y, wreg[5], p);
            p = fmaf(e1.z, wreg[6], p);  p = fmaf(e1.w, wreg[7], p);
            p = fmaf(e2.x, wreg[8], p);  p = fmaf(e2.y, wreg[9], p);
            p = fmaf(e2.z, wreg[10], p); p = fmaf(e2.w, wreg[11], p);
            p = fmaf(e3.x, wreg[12], p); p = fmaf(e3.y, wreg[13], p);
            p = fmaf(e3.z, wreg[14], p); p = fmaf(e3.w, wreg[15], p);
            acc += fmaxf(x[(size_t)s * 64 + lane] + p, 0.f);
        }
        xin[(size_t)n * 64 + lane] = __float2bfloat16(acc);
    }
}

// ---------------- GINE2 gather -----------------------------------------------
#define G2_NPB 16
__global__ __launch_bounds__(256, 2) void gine2_gather(
    const __hip_bfloat16* __restrict__ h, const int* __restrict__ srcv,
    const float* __restrict__ ea, const float* __restrict__ e2W,
    const float* __restrict__ e2b, const int* __restrict__ rowptr,
    const int* __restrict__ eid, __hip_bfloat16* __restrict__ a2, int n0, int n1) {
    int tid = threadIdx.x;
    int half = tid >> 7, lt = tid & 127;
    float wreg[4][16], breg[4];
#pragma unroll
    for (int j = 0; j < 4; j++) {
        int c = lt * 4 + j;
        breg[j] = e2b[c];
#pragma unroll
        for (int k = 0; k < 16; k++) wreg[j][k] = e2W[k * 512 + c];
    }
    int nbase = n0 + blockIdx.x * G2_NPB + half;
#pragma unroll 1
    for (int it = 0; it < G2_NPB / 2; it++) {
        int n = nbase + it * 2;
        if (n >= n1) return;
        short4 hv = *(const short4*)((const short*)(h + (size_t)n * 512) + lt * 4);
        const __hip_bfloat16* hb = (const __hip_bfloat16*)&hv;
        float acc[4];
#pragma unroll
        for (int j = 0; j < 4; j++) acc[j] = __bfloat162float(hb[j]);
        int beg = rowptr[n], end = rowptr[n + 1];
        for (int idx = beg; idx < end; idx++) {
            int e = eid[idx], s = srcv[e];
            const float4* ef = (const float4*)(ea + (size_t)e * 16);
            float4 e0 = ef[0], e1 = ef[1], e2v = ef[2], e3 = ef[3];
            short4 sv = *(const short4*)((const short*)(h + (size_t)s * 512) + lt * 4);
            const __hip_bfloat16* sb = (const __hip_bfloat16*)&sv;
#pragma unroll
            for (int j = 0; j < 4; j++) {
                float p = breg[j];
                p = fmaf(e0.x, wreg[j][0], p);  p = fmaf(e0.y, wreg[j][1], p);
                p = fmaf(e0.z, wreg[j][2], p);  p = fmaf(e0.w, wreg[j][3], p);
                p = fmaf(e1.x, wreg[j][4], p);  p = fmaf(e1.y, wreg[j][5], p);
                p = fmaf(e1.z, wreg[j][6], p);  p = fmaf(e1.w, wreg[j][7], p);
                p = fmaf(e2v.x, wreg[j][8], p); p = fmaf(e2v.y, wreg[j][9], p);
                p = fmaf(e2v.z, wreg[j][10], p);p = fmaf(e2v.w, wreg[j][11], p);
                p = fmaf(e3.x, wreg[j][12], p); p = fmaf(e3.y, wreg[j][13], p);
                p = fmaf(e3.z, wreg[j][14], p); p = fmaf(e3.w, wreg[j][15], p);
                acc[j] += fmaxf(__bfloat162float(sb[j]) + p, 0.f);
            }
        }
        __hip_bfloat16 o[4];
#pragma unroll
        for (int j = 0; j < 4; j++) o[j] = __float2bfloat16(acc[j]);
        *(short4*)((short*)(a2 + (size_t)(n - n0) * 512) + lt * 4) = *(const short4*)o;
    }
}

// ---------------- MFMA GEMM: C[M,N] = A[M,K](bf16) @ B^T[N,K](bf16) ----------
// LDS staging (async global_load_lds), BK=64 (8 drains at K=512), XCD-aware
// 1-D swizzle: the nCol col-tile blocks of one row-tile share id%8 -> same XCD
// -> A-tile L2-resident after first fetch.
template <int MODE>
__global__ __launch_bounds__(256, 3) void mfma_gemm(
    const __hip_bfloat16* __restrict__ A, const __hip_bfloat16* __restrict__ Bhi,
    int M, int K, int N, const float* __restrict__ bias, const float* __restrict__ bng,
    const float* __restrict__ bnb, const int* __restrict__ batch,
    float* __restrict__ psum, __hip_bfloat16* __restrict__ Cout) {
    __shared__ short As[128 * 64];   // 16 KB
    __shared__ short Bh[128 * 64];   // 16 KB
    int nRT = (M + 127) >> 7;
    int nCT = N >> 7;
    int per = nCT << 3;
    int id = blockIdx.x;
    int grp = id / per, wi = id % per;
    int ct = wi >> 3, rx = wi & 7;
    int rt = grp * 8 + rx;
    if (rt >= nRT) return;           // uniform per block: safe w.r.t. barriers
    int r0 = rt * 128, n0 = ct * 128;

    int tid = threadIdx.x;
    int lane = tid & 63;
    int wv = tid >> 6;
    int wm = (wv >> 1) * 64, wn = (wv & 1) * 64;

    f32x4 acc[4][4];
#pragma unroll
    for (int i = 0; i < 4; i++)
#pragma unroll
        for (int j = 0; j < 4; j++) acc[i][j] = (f32x4){0.f, 0.f, 0.f, 0.f};

    int fi = lane & 15, kb = (lane >> 4) * 8;
    for (int k0 = 0; k0 < K; k0 += 64) {
        __syncthreads();
        // stage 128x64 bf16 tiles: 1024 x 16B each, 4 chunks/thread/matrix
#pragma unroll
        for (int j = 0; j < 4; j++) {
            int i = tid + j * 256;           // 0..1023
            int row = i >> 3, cb = i & 7;
            int gA = r0 + row; if (gA >= M) gA = M - 1;
            gl2lds16(A + (size_t)gA * K + k0 + cb * 8, As + wv * 512 + j * 2048);
            gl2lds16(Bhi + (size_t)(n0 + row) * K + k0 + cb * 8, Bh + wv * 512 + j * 2048);
        }
        __syncthreads();
#pragma unroll
        for (int kh = 0; kh < 64; kh += 32) {
            bf16x8 af[4], bhf[4];
#pragma unroll
            for (int mi = 0; mi < 4; mi++)
                af[mi] = *(const bf16x8*)(As + (wm + mi * 16 + fi) * 64 + kb + kh);
#pragma unroll
            for (int ni = 0; ni < 4; ni++)
                bhf[ni] = *(const bf16x8*)(Bh + (wn + ni * 16 + fi) * 64 + kb + kh);
#pragma unroll
            for (int mi = 0; mi < 4; mi++)
#pragma unroll
                for (int ni = 0; ni < 4; ni++)
                    acc[mi][ni] = __builtin_amdgcn_mfma_f32_16x16x32_bf16(
                        af[mi], bhf[ni], acc[mi][ni], 0, 0, 0);
        }
    }
    int col_l = lane & 15, quad = lane >> 4;
#pragma unroll
    for (int mi = 0; mi < 4; mi++) {
        int rbase = r0 + wm + mi * 16 + quad * 4;
#pragma unroll
        for (int ni = 0; ni < 4; ni++) {
            int gcol = n0 + wn + ni * 16 + col_l;
            if (MODE == 0) {
                float b0 = bias[gcol];
#pragma unroll
                for (int reg = 0; reg < 4; reg++) {
                    int grow = rbase + reg;
                    if (grow < M)
                        Cout[(size_t)grow * N + gcol] = __float2bfloat16(acc[mi][ni][reg] + b0);
                }
            } else {
                float b0 = bias[gcol], g0 = bng[gcol], bb0 = bnb[gcol];
                float vv[4];
#pragma unroll
                for (int reg = 0; reg < 4; reg++)
                    vv[reg] = fmaxf(fmaf((acc[mi][ni][reg] + b0) * bn_inv(), g0, bb0), 0.f);
                if (MODE == 1) {
#pragma unroll
                    for (int reg = 0; reg < 4; reg++) {
                        int grow = rbase + reg;
                        if (grow < M) Cout[(size_t)grow * 512 + gcol] = __float2bfloat16(vv[reg]);
                    }
                } else {
                    if (rbase + 3 < M && batch[rbase] == batch[rbase + 3]) {
                        atomicAdd(&psum[(size_t)batch[rbase] * 512 + gcol],
                                  (vv[0] + vv[1]) + (vv[2] + vv[3]));
                    } else {
#pragma unroll
                        for (int reg = 0; reg < 4; reg++) {
                            int grow = rbase + reg;
                            if (grow < M)
                                atomicAdd(&psum[(size_t)batch[grow] * 512 + gcol], vv[reg]);
                        }
                    }
                }
            }
        }
    }
}

static inline int gemm_grid(int M, int N) {
    int nRT = (M + 127) >> 7, nCT = N >> 7;
    int nGrp = (nRT + 7) >> 3;
    return nGrp * 8 * nCT;
}

// ---------------- node counts per graph --------------------------------------
__global__ void count_nodes(const int* __restrict__ batch, float* __restrict__ cnt) {
    int i = blockIdx.x * 256 + threadIdx.x;
    if (i < N_NODESC) atomicAdd(&cnt[batch[i]], 1.0f);
}

// ---------------- finalize pool + assemble xn [B,7,512] bf16 -----------------
__global__ void build_xn(const float* __restrict__ psum, const float* __restrict__ cnt,
                         const float* __restrict__ ecfp, const float* __restrict__ topo,
                         const float* __restrict__ maccs, const float* __restrict__ estate,
                         const float* __restrict__ rdkit2d, const float* __restrict__ phar2d,
                         __hip_bfloat16* __restrict__ xn) {
    int i = blockIdx.x * 256 + threadIdx.x;
    if (i >= BG * 512) return;
    int bidx = i >> 9, c = i & 511;
    float cv = fmaxf(cnt[bidx], 1.0f);
    __hip_bfloat16* o = xn + (size_t)bidx * 7 * 512;
    o[c] = __float2bfloat16(psum[i] / cv);
    o[512 + c] = __float2bfloat16(ecfp[i]);
    o[2 * 512 + c] = __float2bfloat16(topo[i]);
    o[3 * 512 + c] = __float2bfloat16(maccs[i]);
    o[4 * 512 + c] = __float2bfloat16(estate[i]);
    o[5 * 512 + c] = __float2bfloat16(rdkit2d[i]);
    o[6 * 512 + c] = __float2bfloat16(phar2d[i]);
}

// ---------------- GAT attention (fused gl|gr layout: C[B*7][4096]) -----------
__global__ void gat_attn(const __hip_bfloat16* __restrict__ cg,
                         const float* __restrict__ att, const float* __restrict__ bias,
                         const float* __restrict__ bng, const float* __restrict__ bnb,
                         __hip_bfloat16* __restrict__ zout) {
    int b = blockIdx.x;
    int tid = threadIdx.x;
    int wave = tid >> 6, lane = tid & 63;
    __shared__ float logits[13][4];
    __shared__ float alpha[13][4];
    const size_t base = (size_t)b * 7 * 4096;
    for (int p = wave; p < 52; p += 4) {
        int e = p >> 2, hh = p & 3;
        int se = (e < 7) ? 0 : (e - 6);
        int de = (e < 6) ? (e + 1) : ((e == 6) ? 0 : (e - 6));
        const __hip_bfloat16* glp = cg + base + (size_t)se * 4096 + hh * 512;
        const __hip_bfloat16* grp = cg + base + (size_t)de * 4096 + 2048 + hh * 512;
        const float* ap = att + hh * 512;
        float s = 0.f;
#pragma unroll
        for (int j = 0; j < 8; j++) {
            int c = lane + j * 64;
            float v = __bfloat162float(glp[c]) + __bfloat162float(grp[c]);
            v = (v >= 0.f) ? v : 0.2f * v;
            s = fmaf(v, ap[c], s);
        }
#pragma unroll
        for (int off = 32; off; off >>= 1) s += __shfl_down(s, off);
        if (lane == 0) logits[e][hh] = s;
    }
    __syncthreads();
    if (tid < 24) {
        int n = 1 + (tid >> 2), hh = tid & 3;
        float la = logits[n - 1][hh], lb = logits[6 + n][hh];
        float m = fmaxf(la, lb);
        float ea = __expf(la - m), eb = __expf(lb - m);
        float inv = 1.f / (ea + eb);
        alpha[n - 1][hh] = ea * inv;
        alpha[6 + n][hh] = eb * inv;
    } else if (tid < 28) {
        alpha[6][tid & 3] = 1.f;
    }
    __syncthreads();
    for (int i = tid; i < 7 * 512; i += 256) {
        int n = i >> 9, c = i & 511;
        float v = 0.f;
        if (n == 0) {
#pragma unroll
            for (int hh = 0; hh < 4; hh++)
                v = fmaf(alpha[6][hh],
                         __bfloat162float(cg[base + (size_t)hh * 512 + c]), v);
        } else {
#pragma unroll
            for (int hh = 0; hh < 4; hh++) {
                v = fmaf(alpha[n - 1][hh],
                         __bfloat162float(cg[base + (size_t)hh * 512 + c]), v);
                v = fmaf(alpha[6 + n][hh],
                         __bfloat162float(cg[base + (size_t)n * 4096 + hh * 512 + c]), v);
            }
        }
        v = fmaf(v, 0.25f, bias[c]);
        v = fmaf(v * bn_inv(), bng[c], bnb[c]);
        zout[(size_t)b * 7 * 512 + i] = __float2bfloat16(fmaxf(v, 0.f));
    }
}

// ---------------- final fc ----------------------------------------------------
__global__ void final_fc(const __hip_bfloat16* __restrict__ z, const float* __restrict__ fcW,
                         const float* __restrict__ fcb, float* __restrict__ out) {
    int b = blockIdx.x * 4 + (threadIdx.x >> 6);
    int lane = threadIdx.x & 63;
    if (b >= BG) return;
    const __hip_bfloat16* row = z + (size_t)b * 7 * 512;
    float s = 0.f;
#pragma unroll
    for (int j = 0; j < 8; j++)
        s = fmaf(__bfloat162float(row[lane + j * 64]), fcW[lane + j * 64], s);
#pragma unroll
    for (int off = 32; off; off >>= 1) s += __shfl_down(s, off);
    if (lane == 0) out[b] = s + fcb[0];
}

extern "C" void kernel_launch(void* const* d_in, const int* in_sizes, int n_in,
                              void* d_out, int out_size, void* d_ws, size_t ws_size,
                              hipStream_t stream) {
    const float* x = (const float*)d_in[0];
    const int* eidx = (const int*)d_in[1];
    const float* eattr = (const float*)d_in[2];
    const int* batch = (const int*)d_in[3];
    const float* ecfp = (const float*)d_in[4];
    const float* topo = (const float*)d_in[5];
    const float* maccs = (const float*)d_in[6];
    const float* estate = (const float*)d_in[7];
    const float* rdkit2d = (const float*)d_in[8];
    const float* phar2d = (const float*)d_in[9];
    const float* g1_W = (const float*)d_in[10];
    const float* g1_b = (const float*)d_in[11];
    const float* e1_W = (const float*)d_in[12];
    const float* e1_b = (const float*)d_in[13];
    const float* bn1_g = (const float*)d_in[14];
    const float* bn1_b = (const float*)d_in[15];
    const float* g2_W = (const float*)d_in[16];
    const float* g2_b = (const float*)d_in[17];
    const float* e2_W = (const float*)d_in[18];
    const float* e2_b = (const float*)d_in[19];
    const float* bn2_g = (const float*)d_in[20];
    const float* bn2_b = (const float*)d_in[21];
    const float* gat1_Wl = (const float*)d_in[22];
    const float* gat1_bl = (const float*)d_in[23];
    const float* gat1_Wr = (const float*)d_in[24];
    const float* gat1_br = (const float*)d_in[25];
    const float* gat1_att = (const float*)d_in[26];
    const float* gat1_bias = (const float*)d_in[27];
    const float* bn3_g = (const float*)d_in[28];
    const float* bn3_b = (const float*)d_in[29];
    const float* gat2_Wl = (const float*)d_in[30];
    const float* gat2_bl = (const float*)d_in[31];
    const float* gat2_Wr = (const float*)d_in[32];
    const float* gat2_br = (const float*)d_in[33];
    const float* gat2_att = (const float*)d_in[34];
    const float* gat2_bias = (const float*)d_in[35];
    const float* bn4_g = (const float*)d_in[36];
    const float* bn4_b = (const float*)d_in[37];
    const float* fc_W = (const float*)d_in[38];
    const float* fc_b = (const float*)d_in[39];
    float* out = (float*)d_out;

    const size_t NEEDED = 194682880ull;
    if (ws_size < NEEDED) {
        zero_out<<<(BG + 255) / 256, 256, 0, stream>>>(out, BG);
        return;
    }
    char* w = (char*)d_ws;
    __hip_bfloat16* H = (__hip_bfloat16*)w;
    __hip_bfloat16* CG = (__hip_bfloat16*)w;
    __hip_bfloat16* A2 = (__hip_bfloat16*)(w + 102400000);
    __hip_bfloat16* GW12 = (__hip_bfloat16*)(w + 117440512);
    __hip_bfloat16* GW34 = (__hip_bfloat16*)(w + 121634816);
    __hip_bfloat16* Z1B = (__hip_bfloat16*)(w + 125829120);
    float* B12 = (float*)(w + 140509184);
    float* B34 = (float*)(w + 140525568);

    char* C = w + 161120256;
    __hip_bfloat16* XIN = (__hip_bfloat16*)C;
    __hip_bfloat16* XNB = (__hip_bfloat16*)C;
    __hip_bfloat16* Z2B = (__hip_bfloat16*)(C + 14680064);
    int* ROWPTR = (int*)(C + 14680064);
    int* CURSOR = (int*)(C + 15080192);
    int* EID = (int*)(C + 15480320);
    int* DEG = (int*)(C + 16280320);
    __hip_bfloat16* G1W = (__hip_bfloat16*)(C + 16680320);
    __hip_bfloat16* G2W = (__hip_bfloat16*)(C + 16745856);
    int* BSUM = (int*)(C + 17270144);

    float* PS = (float*)(w + 190480384);
    float* PC = (float*)(w + 194674688);

    const int* src = eidx;
    const int* dst = eidx + N_EDGESC;

    // ---- CSR build ----
    zero_int<<<(N_NODESC + 255) / 256, 256, 0, stream>>>(DEG, N_NODESC);
    zero_f4<<<(BG * 512 / 4 + 255) / 256, 256, 0, stream>>>((float4*)PS, BG * 512 / 4);
    zero_f4<<<(BG / 4 + 255) / 256, 256, 0, stream>>>((float4*)PC, BG / 4);
    hist_dst<<<(N_EDGESC + 255) / 256, 256, 0, stream>>>(dst, DEG);
    const int NB = (N_NODESC + 1023) / 1024;  // 98
    scan_bsums<<<NB, 256, 0, stream>>>(DEG, BSUM, N_NODESC);
    scan_top<<<1, 64, 0, stream>>>(BSUM, NB, ROWPTR + N_NODESC);
    scan_final<<<NB, 256, 0, stream>>>(DEG, BSUM, ROWPTR, CURSOR, N_NODESC);
    scatter_eid<<<(N_EDGESC + 255) / 256, 256, 0, stream>>>(dst, CURSOR, EID);

    // ---- GINE weight prep ----
    transpose_w<<<dim3(1, 8), 256, 0, stream>>>(g1_W, G1W, 64, 512);
    transpose_w<<<dim3(8, 8), 256, 0, stream>>>(g2_W, G2W, 512, 512);

    // ---- GINE1 ----
    gine1_gather<<<(N_NODESC + 4 * G1_NPW - 1) / (4 * G1_NPW), 256, 0, stream>>>(
        x, src, eattr, e1_W, e1_b, ROWPTR, EID, XIN);
    mfma_gemm<1><<<gemm_grid(N_NODESC, 512), 256, 0, stream>>>(
        XIN, G1W, N_NODESC, 64, 512, g1_b, bn1_g, bn1_b, nullptr, nullptr, H);
    count_nodes<<<(N_NODESC + 255) / 256, 256, 0, stream>>>(batch, PC);

    // ---- GINE2: 2 chunks of 50k nodes ----
    for (int c0n = 0; c0n < N_NODESC; c0n += 50000) {
        int c1n = c0n + 50000;
        int rows = 50000;
        gine2_gather<<<(rows + G2_NPB - 1) / G2_NPB, 256, 0, stream>>>(
            H, src, eattr, e2_W, e2_b, ROWPTR, EID, A2, c0n, c1n);
        mfma_gemm<2><<<gemm_grid(rows, 512), 256, 0, stream>>>(
            A2, G2W, rows, 512, 512, g2_b, bn2_g, bn2_b, batch + c0n, PS, nullptr);
    }

    // ---- GAT weight prep (H and A2 dead) ----
    transpose_w<<<dim3(8, 32), 256, 0, stream>>>(gat1_Wl, GW12, 512, 2048);
    transpose_w<<<dim3(8, 32), 256, 0, stream>>>(gat1_Wr, GW12 + (size_t)2048 * 512, 512, 2048);
    transpose_w<<<dim3(8, 32), 256, 0, stream>>>(gat2_Wl, GW34, 512, 2048);
    transpose_w<<<dim3(8, 32), 256, 0, stream>>>(gat2_Wr, GW34 + (size_t)2048 * 512, 512, 2048);
    concat_bias<<<8, 256, 0, stream>>>(gat1_bl, gat1_br, B12);
    concat_bias<<<8, 256, 0, stream>>>(gat2_bl, gat2_br, B34);

    // ---- pool -> xn ----
    build_xn<<<(BG * 512) / 256, 256, 0, stream>>>(PS, PC, ecfp, topo, maccs, estate,
                                                   rdkit2d, phar2d, XNB);
    // ---- GAT layer 1 (fused L|R: N = 4096) ----
    const int MGAT = BG * 7;  // 14336
    mfma_gemm<0><<<gemm_grid(MGAT, 4096), 256, 0, stream>>>(
        XNB, GW12, MGAT, 512, 4096, B12, nullptr, nullptr, nullptr, nullptr, CG);
    gat_attn<<<BG, 256, 0, stream>>>(CG, gat1_att, gat1_bias, bn3_g, bn3_b, Z1B);
    // ---- GAT layer 2 ----
    mfma_gemm<0><<<gemm_grid(MGAT, 4096), 256, 0, stream>>>(
        Z1B, GW34, MGAT, 512, 4096, B34, nullptr, nullptr, nullptr, nullptr, CG);
    gat_attn<<<BG, 256, 0, stream>>>(CG, gat2_att, gat2_bias, bn4_g, bn4_b, Z2B);
    // ---- final fc ----
    final_fc<<<BG / 4, 256, 0, stream>>>(Z2B, fc_W, fc_b, out);
}